// Round 1
// baseline (301.426 us; speedup 1.0000x reference)
//
#include <hip/hip_runtime.h>
#include <hip/hip_bf16.h>

// Pairwise upper-triangular products:
//   x = X.reshape(B, 512); out[b, p] = x[b, ii[p]] * x[b, jj[p]]
//   (ii, jj) = triu_indices(512), row-major enumeration.
// Write-BW-bound: 538 MB out vs 2 MB in.
//
// Block strategy: one block handles rows k and 511-k of batch b
// (lengths (512-k) + (k+1) = 513, uniform work per block).
// Row i output offset: off(i) = i*512 - i*(i-1)/2 (contiguous run of 512-i).

#define ELE 512
#define NPAIRS (ELE * (ELE + 1) / 2)   // 131328

__global__ __launch_bounds__(256) void pairmul_kernel(
    const float* __restrict__ X, float* __restrict__ out) {
    const int bid = blockIdx.x;
    const int b   = bid >> 8;      // batch index (256 row-pair blocks per batch)
    const int k   = bid & 255;     // row-pair index 0..255

    const float* xb = X + (size_t)b * ELE;
    float* ob = out + (size_t)b * NPAIRS;

    // Stage the 512-float x row in LDS (2 KB).
    __shared__ float xs[ELE];
    xs[threadIdx.x]       = xb[threadIdx.x];
    xs[threadIdx.x + 256] = xb[threadIdx.x + 256];
    __syncthreads();

    // Row i1 = k: length 512-k
    {
        const int i = k;
        const int L = ELE - i;
        const size_t off = (size_t)i * ELE - (size_t)i * (i - 1) / 2;
        const float xi = xs[i];
        for (int j = threadIdx.x; j < L; j += 256) {
            ob[off + j] = xi * xs[i + j];
        }
    }
    // Row i2 = 511-k: length k+1
    {
        const int i = ELE - 1 - k;
        const int L = ELE - i;
        const size_t off = (size_t)i * ELE - (size_t)i * (i - 1) / 2;
        const float xi = xs[i];
        for (int j = threadIdx.x; j < L; j += 256) {
            ob[off + j] = xi * xs[i + j];
        }
    }
}

extern "C" void kernel_launch(void* const* d_in, const int* in_sizes, int n_in,
                              void* d_out, int out_size, void* d_ws, size_t ws_size,
                              hipStream_t stream) {
    const float* X = (const float*)d_in[0];
    float* out = (float*)d_out;

    const int B = in_sizes[0] / ELE;   // 1024
    // 256 row-pair blocks per batch element
    dim3 grid(B * 256);
    dim3 block(256);
    pairmul_kernel<<<grid, block, 0, stream>>>(X, out);
}

// Round 2
// 173.017 us; speedup vs baseline: 1.7422x; 1.7422x over previous
//
#include <hip/hip_runtime.h>
#include <hip/hip_bf16.h>

// out[b, p] = x[b, ii[p]] * x[b, jj[p]], (ii,jj)=triu_indices(512), row-major.
// Write-BW-bound: ~525 MB out, 2 MB in. Strategy: index output by flat pair
// group g (4 floats), invert p -> row i via triangular formula, float4 stores.
//
// off(i) = i*(1025-i)/2 ; row i spans [off(i), off(i+1)), length 512-i.

#define ELE 512
#define NPAIRS 131328            // 512*513/2
#define GROUPS 32832             // NPAIRS/4
#define BLOCKS_PER_BATCH 16
#define GROUPS_PER_BLOCK 2052    // GROUPS/BLOCKS_PER_BATCH

__device__ __forceinline__ int row_off(int i) {
    return (i * (1025 - i)) >> 1;
}

__device__ __forceinline__ int row_of(int p) {
    // i = floor((1025 - sqrt(1025^2 - 8p)) / 2), then integer fixup.
    float s = sqrtf((float)(1050625 - 8 * p));
    int i = (int)((1025.0f - s) * 0.5f);
    if (i < 0) i = 0;
    if (i > 511) i = 511;
    while (row_off(i + 1) <= p) ++i;
    while (i > 0 && row_off(i) > p) --i;
    return i;
}

__global__ __launch_bounds__(256) void pairmul4_kernel(
    const float* __restrict__ X, float* __restrict__ out) {
    const int bid = blockIdx.x;
    const int b = bid / BLOCKS_PER_BATCH;
    const int c = bid % BLOCKS_PER_BATCH;

    const float* xb = X + (size_t)b * ELE;
    float4* ob = (float4*)(out + (size_t)b * NPAIRS);  // 16B-aligned per batch

    __shared__ float xs[ELE];
    xs[threadIdx.x]       = xb[threadIdx.x];
    xs[threadIdx.x + 256] = xb[threadIdx.x + 256];
    __syncthreads();

    const int glo = c * GROUPS_PER_BLOCK;
    const int ghi = glo + GROUPS_PER_BLOCK;

    for (int g = glo + (int)threadIdx.x; g < ghi; g += 256) {
        const int p = g << 2;
        int i = row_of(p);
        float4 v;
        if (p + 3 < row_off(i + 1)) {
            // Fast path: whole group within row i (~98.4% of groups)
            const float xi = xs[i];
            const int j = i + (p - row_off(i));
            v.x = xi * xs[j];
            v.y = xi * xs[j + 1];
            v.z = xi * xs[j + 2];
            v.w = xi * xs[j + 3];
        } else {
            // Group spans a row boundary (rows only get shorter; walk forward)
            float r[4];
            int ii = i;
            #pragma unroll
            for (int t = 0; t < 4; ++t) {
                const int pt = p + t;
                while (row_off(ii + 1) <= pt) ++ii;
                r[t] = xs[ii] * xs[ii + (pt - row_off(ii))];
            }
            v = make_float4(r[0], r[1], r[2], r[3]);
        }
        ob[g] = v;
    }
}

extern "C" void kernel_launch(void* const* d_in, const int* in_sizes, int n_in,
                              void* d_out, int out_size, void* d_ws, size_t ws_size,
                              hipStream_t stream) {
    const float* X = (const float*)d_in[0];
    float* out = (float*)d_out;

    const int B = in_sizes[0] / ELE;   // 1024
    dim3 grid(B * BLOCKS_PER_BATCH);
    dim3 block(256);
    pairmul4_kernel<<<grid, block, 0, stream>>>(X, out);
}

// Round 3
// 109.463 us; speedup vs baseline: 2.7537x; 1.5806x over previous
//
#include <hip/hip_runtime.h>
#include <hip/hip_bf16.h>

// out[b, p] = x[b, ii[p]] * x[b, jj[p]], (ii,jj)=triu_indices(512), row-major.
// Write-BW-bound: ~525 MB out, 2 MB in. Flat float4-group indexing with
// triangular inversion; XOR-swizzled LDS to kill the 8-way bank conflict
// caused by lane-stride-4-float reads (lanes l, l+8, ... shared a bank).
//
// off(i) = i*(1025-i)/2 ; row i spans [off(i), off(i+1)), length 512-i.

#define ELE 512
#define NPAIRS 131328            // 512*513/2
#define GROUPS 32832             // NPAIRS/4
#define BLOCKS_PER_BATCH 16
#define GROUPS_PER_BLOCK 2052    // GROUPS/BLOCKS_PER_BATCH

__device__ __forceinline__ int row_off(int i) {
    return (i * (1025 - i)) >> 1;
}

// XOR swizzle on float index: spreads stride-4 lane patterns across banks.
// Bijective within each 32-float window (only bits [4:2] are XORed).
__device__ __forceinline__ int swz(int f) {
    return f ^ (((f >> 5) & 7) << 2);
}

__global__ __launch_bounds__(256) void pairmul4_kernel(
    const float* __restrict__ X, float* __restrict__ out) {
    const int bid = blockIdx.x;
    const int b = bid / BLOCKS_PER_BATCH;
    const int c = bid % BLOCKS_PER_BATCH;

    const float* xb = X + (size_t)b * ELE;
    float4* ob = (float4*)(out + (size_t)b * NPAIRS);  // 16B-aligned per batch

    __shared__ float xs[ELE];
    xs[swz(threadIdx.x)]       = xb[threadIdx.x];
    xs[swz(threadIdx.x + 256)] = xb[threadIdx.x + 256];
    __syncthreads();

    const int glo = c * GROUPS_PER_BLOCK;
    const int ghi = glo + GROUPS_PER_BLOCK;

    for (int g = glo + (int)threadIdx.x; g < ghi; g += 256) {
        const int p = g << 2;
        // Triangular inversion: i = floor((1025 - sqrt(1025^2 - 8p))/2)
        float s = sqrtf((float)(1050625 - 8 * p));
        int i = (int)((1025.0f - s) * 0.5f);
        i = min(max(i, 0), 511);
        int o0 = row_off(i);            // start of row i
        int o1 = o0 + (ELE - i);        // start of row i+1
        while (o1 <= p) { ++i; o0 = o1; o1 += (ELE - i); }
        while (o0 > p)  { --i; o1 = o0; o0 -= (ELE - i); }

        float4 v;
        if (p + 3 < o1) {
            // Fast path: whole group within row i (~98.4% of groups)
            const float xi = xs[swz(i)];
            const int j = i + (p - o0);
            v.x = xi * xs[swz(j)];
            v.y = xi * xs[swz(j + 1)];
            v.z = xi * xs[swz(j + 2)];
            v.w = xi * xs[swz(j + 3)];
        } else {
            // Group spans a row boundary (rows only get shorter; walk forward)
            float r[4];
            int ii = i, oo0 = o0, oo1 = o1;
            #pragma unroll
            for (int t = 0; t < 4; ++t) {
                const int pt = p + t;
                while (oo1 <= pt) { ++ii; oo0 = oo1; oo1 += (ELE - ii); }
                r[t] = xs[swz(ii)] * xs[swz(ii + (pt - oo0))];
            }
            v = make_float4(r[0], r[1], r[2], r[3]);
        }
        ob[g] = v;
    }
}

extern "C" void kernel_launch(void* const* d_in, const int* in_sizes, int n_in,
                              void* d_out, int out_size, void* d_ws, size_t ws_size,
                              hipStream_t stream) {
    const float* X = (const float*)d_in[0];
    float* out = (float*)d_out;

    const int B = in_sizes[0] / ELE;   // 1024
    dim3 grid(B * BLOCKS_PER_BATCH);
    dim3 block(256);
    pairmul4_kernel<<<grid, block, 0, stream>>>(X, out);
}